// Round 7
// baseline (69.656 us; speedup 1.0000x reference)
//
#include <hip/hip_runtime.h>
#include <math.h>

#define NQ   11
#define DIM  2048        // 2^11
#define NL   6

typedef float v2f __attribute__((ext_vector_type(2)));   // (re, im)

// GF(2)-linear swizzle (proven R3-R5 for all k1 LDS patterns @256 threads)
__host__ __device__ constexpr int swzA(int x) {
    return x ^ ((x >> 6) & 31) ^ ((x & 2) << 3) ^ ((x & 1) << 3);
}

__device__ __forceinline__ float2 cfma2(float2 u, float2 a, float2 v, float2 b) {
    float2 r;
    r.x = u.x*a.x - u.y*a.y + v.x*b.x - v.y*b.y;
    r.y = u.x*a.y + u.y*a.x + v.x*b.y + v.y*b.x;
    return r;
}

// ================= kernel 1: all sample-independent work, 1 block ============
// (byte-for-byte the proven R5 version)
__global__ __launch_bounds__(256) void qnn_shared_kernel(
    const float* __restrict__ P,      // (NL, NQ, 3)
    float2* __restrict__ ws)          // out: 2048 float2, natural order
{
    __shared__ float2 lds[DIM];
    __shared__ float2 G[NL*NQ][4];
    const int t = threadIdx.x;        // 8 bits

    if (t < NL*NQ) {
        const float p0 = P[t*3+0], p1 = P[t*3+1], p2 = P[t*3+2];
        const float th = 0.5f*p1;
        const float c  = cosf(th), s = sinf(th);
        const float al = 0.5f*(p0+p2), be = 0.5f*(p0-p2);
        const float ca = cosf(al), sa = sinf(al);
        const float cb = cosf(be), sb = sinf(be);
        G[t][0] = make_float2( c*ca, -c*sa);
        G[t][1] = make_float2(-s*cb, -s*sb);
        G[t][2] = make_float2( s*cb, -s*sb);
        G[t][3] = make_float2( c*ca,  c*sa);
    }

    const int a0w = swzA(t);                          // X1 write (k<<8)
    const int a1b = swzA(((t>>5)<<8) | (t&31));       // X1 read / X2 write (k<<5)
    const int a2b = swzA(((t>>2)<<5) | (t&3));        // X2 read / X3 write (k<<2)
    const int a3b = swzA(t ^ (t>>1));                 // X3 perm-gather read
    const int natb = ((t>>2)<<5) | (t&3);             // ws natural-order base

    float2 a[8];
    #pragma unroll
    for (int k = 0; k < 8; ++k) a[k] = make_float2(0.f, 0.f);
    if (t == 0) a[0] = make_float2(1.f, 0.f);
    __syncthreads();   // G ready

    #define CG(g_, rb_) { \
        const float2 U00=G[g_][0], U01=G[g_][1], U10=G[g_][2], U11=G[g_][3]; \
        _Pragma("unroll") \
        for (int kk = 0; kk < 8; ++kk) if (!(kk & (rb_))) { \
            const float2 a0 = a[kk], a1 = a[kk|(rb_)]; \
            a[kk]       = cfma2(U00, a0, U01, a1); \
            a[kk|(rb_)] = cfma2(U10, a0, U11, a1); \
        } }

    #define SG(g_, m_, b_) { \
        const float2 ca_ = (b_) ? G[g_][3] : G[g_][0]; \
        const float2 cb_ = (b_) ? G[g_][2] : G[g_][1]; \
        _Pragma("unroll") \
        for (int kk = 0; kk < 8; ++kk) { \
            float2 p; \
            p.x = __shfl_xor(a[kk].x, m_); \
            p.y = __shfl_xor(a[kk].y, m_); \
            a[kk] = cfma2(ca_, a[kk], cb_, p); \
        } }

    for (int l = 0; l < NL; ++l) {
        const int g0 = l*NQ;
        CG(g0+0, 4) CG(g0+1, 2) CG(g0+2, 1)          // qubits 0,1,2 (bits 10,9,8)

        #pragma unroll
        for (int k = 0; k < 8; ++k) lds[a0w ^ swzA(k<<8)] = a[k];
        __syncthreads();
        #pragma unroll
        for (int k = 0; k < 8; ++k) a[k] = lds[a1b ^ swzA(k<<5)];
        __syncthreads();
        CG(g0+3, 4) CG(g0+4, 2) CG(g0+5, 1)          // qubits 3,4,5 (bits 7,6,5)

        #pragma unroll
        for (int k = 0; k < 8; ++k) lds[a1b ^ swzA(k<<5)] = a[k];
        __syncthreads();
        #pragma unroll
        for (int k = 0; k < 8; ++k) a[k] = lds[a2b ^ swzA(k<<2)];
        __syncthreads();
        CG(g0+6, 4) CG(g0+7, 2) CG(g0+8, 1)          // qubits 6,7,8 (bits 4,3,2)

        SG(g0+9, 2, (t>>1)&1)                        // qubit 9 (bit 1)
        SG(g0+10, 1, t&1)                            // qubit 10 (bit 0)

        if (l < NL-1) {
            #pragma unroll
            for (int k = 0; k < 8; ++k) lds[a2b ^ swzA(k<<2)] = a[k];
            __syncthreads();
            #pragma unroll
            for (int k = 0; k < 8; ++k)
                a[k] = lds[a3b ^ swzA((k<<8) ^ (k<<7))];   // src = g((k<<8)|t)
            __syncthreads();
        } else {
            #pragma unroll
            for (int k = 0; k < 8; ++k) ws[natb | (k<<2)] = a[k];
        }
    }
    #undef CG
    #undef SG
}

// ========= kernel 2: wave-autonomous, one sample per 64-lane wave ============
// 32 amps/lane: index bits 10..6 = reg bits (qubits 0..4), bits 5..0 = lane
// bits (qubits 5..10). No __shared__, no barriers. CNOT perm = static reg
// rename k->k^(k>>1) + lane bpermute (lane^(lane>>1), ^32 for odd k).
__global__ __launch_bounds__(256, 4) void qnn_last_kernel(
    const float* __restrict__ X,      // (B, NQ)
    const float2* __restrict__ S5,    // shared state, natural order
    float2* __restrict__ out)         // (B, DIM)
{
    const int lane = threadIdx.x & 63;
    const int wid  = threadIdx.x >> 6;
    const int b    = blockIdx.x * 4 + wid;

    // lane q (q<11) holds (cos,sin) of x_q/2; broadcast at use via __shfl
    float vc = 1.f, vs = 0.f;
    if (lane < NQ) {
        const float tx = 0.5f * X[(size_t)b*NQ + lane];
        vc = cosf(tx); vs = sinf(tx);
    }

    // load: reg k holds amp i = (k<<6)|lane   (512 B/wave per load, L2-hit)
    v2f a[32];
    #pragma unroll
    for (int k = 0; k < 32; ++k) {
        const float2 t = S5[(k<<6) | lane];
        a[k] = (v2f){t.x, t.y};
    }

    // register-bit RY butterfly, qubit q_ on reg bit rb_
    #define RG(q_, rb_) { \
        const float c = __shfl(vc, q_), s = __shfl(vs, q_); \
        _Pragma("unroll") \
        for (int kk = 0; kk < 32; ++kk) if (!(kk & (rb_))) { \
            const v2f a0 = a[kk], a1 = a[kk|(rb_)]; \
            a[kk]       = c*a0 - s*a1; \
            a[kk|(rb_)] = s*a0 + c*a1; \
        } }

    // lane-bit RY butterfly, qubit q_ on lane mask m_
    // bit=0: n = c*self - s*partner ; bit=1: n = c*self + s*partner
    #define LG(q_, m_) { \
        const float c = __shfl(vc, q_), s = __shfl(vs, q_); \
        const float sg = (lane & (m_)) ? s : -s; \
        _Pragma("unroll") \
        for (int kk = 0; kk < 32; ++kk) { \
            v2f p; \
            p.x = __shfl_xor(a[kk].x, m_); \
            p.y = __shfl_xor(a[kk].y, m_); \
            a[kk] = c*a[kk] + sg*p; \
        } }

    RG(0,16) RG(1,8) RG(2,4) RG(3,2) RG(4,1)     // qubits 0..4 (bits 10..6)
    LG(5,32) LG(6,16) LG(7,8) LG(8,4) LG(9,2) LG(10,1)   // qubits 5..10

    // CNOT perm + coalesced store: out[(k<<6)|lane] = state[g(o)], g(o)=o^(o>>1)
    // src reg = k^(k>>1) (static), src lane = lane^(lane>>1) (^32 if k odd)
    const int i0 = lane ^ (lane >> 1);
    const int i1 = i0 ^ 32;
    float2* o = out + (size_t)b * DIM + lane;
    #pragma unroll
    for (int k = 0; k < 32; ++k) {
        const int sk = k ^ (k >> 1);
        float2 v;
        v.x = __shfl(a[sk].x, (k & 1) ? i1 : i0);
        v.y = __shfl(a[sk].y, (k & 1) ? i1 : i0);
        o[k<<6] = v;                 // 512 B/wave contiguous
    }
    #undef RG
    #undef LG
}

extern "C" void kernel_launch(void* const* d_in, const int* in_sizes, int n_in,
                              void* d_out, int out_size, void* d_ws, size_t ws_size,
                              hipStream_t stream) {
    const float* X = (const float*)d_in[0];   // (B, NQ) float32
    const float* P = (const float*)d_in[1];   // (NL, NQ, 3) float32
    float2* out = (float2*)d_out;
    float2* ws  = (float2*)d_ws;              // 16 KB shared state
    const int B = in_sizes[0] / NQ;           // 8192
    qnn_shared_kernel<<<1, 256, 0, stream>>>(P, ws);
    qnn_last_kernel<<<B/4, 256, 0, stream>>>(X, ws, out);
}

// Round 8
// 52.459 us; speedup vs baseline: 1.3278x; 1.3278x over previous
//
#include <hip/hip_runtime.h>
#include <math.h>

#define NQ   11
#define DIM  2048        // 2^11
#define NL   6

typedef float v2f __attribute__((ext_vector_type(2)));   // (re, im)

// GF(2)-linear swizzles (R3-R5 proven conflict-free for these pattern sets)
__host__ __device__ constexpr int swzA(int x) {
    return x ^ ((x >> 6) & 31) ^ ((x & 2) << 3) ^ ((x & 1) << 3);
}
__host__ __device__ constexpr int swzB(int x) {
    return x ^ ((x >> 7) & 7) ^ ((x >> 3) & 14) ^ ((x >> 6) & 8);
}

__device__ __forceinline__ float2 cfma2(float2 u, float2 a, float2 v, float2 b) {
    float2 r;
    r.x = u.x*a.x - u.y*a.y + v.x*b.x - v.y*b.y;
    r.y = u.x*a.y + u.y*a.x + v.x*b.y + v.y*b.x;
    return r;
}

// DPP lane-xor (VALU pipe, not LDS): CTRL 177=xor1, 27=xor3, 0x141=xor7
template<int CTRL>
__device__ __forceinline__ v2f dpp_xor(v2f v) {
    const int x = __builtin_amdgcn_update_dpp(
        0, __float_as_int(v.x), CTRL, 0xF, 0xF, true);
    const int y = __builtin_amdgcn_update_dpp(
        0, __float_as_int(v.y), CTRL, 0xF, 0xF, true);
    v2f r; r.x = __int_as_float(x); r.y = __int_as_float(y);
    return r;
}

// ================= kernel 1: all sample-independent work, 1 block ============
// (byte-for-byte the proven R5 version)
__global__ __launch_bounds__(256) void qnn_shared_kernel(
    const float* __restrict__ P,      // (NL, NQ, 3)
    float2* __restrict__ ws)          // out: 2048 float2, natural order
{
    __shared__ float2 lds[DIM];
    __shared__ float2 G[NL*NQ][4];
    const int t = threadIdx.x;        // 8 bits

    if (t < NL*NQ) {
        const float p0 = P[t*3+0], p1 = P[t*3+1], p2 = P[t*3+2];
        const float th = 0.5f*p1;
        const float c  = cosf(th), s = sinf(th);
        const float al = 0.5f*(p0+p2), be = 0.5f*(p0-p2);
        const float ca = cosf(al), sa = sinf(al);
        const float cb = cosf(be), sb = sinf(be);
        G[t][0] = make_float2( c*ca, -c*sa);
        G[t][1] = make_float2(-s*cb, -s*sb);
        G[t][2] = make_float2( s*cb, -s*sb);
        G[t][3] = make_float2( c*ca,  c*sa);
    }

    const int a0w = swzA(t);                          // X1 write (k<<8)
    const int a1b = swzA(((t>>5)<<8) | (t&31));       // X1 read / X2 write (k<<5)
    const int a2b = swzA(((t>>2)<<5) | (t&3));        // X2 read / X3 write (k<<2)
    const int a3b = swzA(t ^ (t>>1));                 // X3 perm-gather read
    const int natb = ((t>>2)<<5) | (t&3);             // ws natural-order base

    float2 a[8];
    #pragma unroll
    for (int k = 0; k < 8; ++k) a[k] = make_float2(0.f, 0.f);
    if (t == 0) a[0] = make_float2(1.f, 0.f);
    __syncthreads();   // G ready

    #define CG(g_, rb_) { \
        const float2 U00=G[g_][0], U01=G[g_][1], U10=G[g_][2], U11=G[g_][3]; \
        _Pragma("unroll") \
        for (int kk = 0; kk < 8; ++kk) if (!(kk & (rb_))) { \
            const float2 a0 = a[kk], a1 = a[kk|(rb_)]; \
            a[kk]       = cfma2(U00, a0, U01, a1); \
            a[kk|(rb_)] = cfma2(U10, a0, U11, a1); \
        } }

    #define SG(g_, m_, b_) { \
        const float2 ca_ = (b_) ? G[g_][3] : G[g_][0]; \
        const float2 cb_ = (b_) ? G[g_][2] : G[g_][1]; \
        _Pragma("unroll") \
        for (int kk = 0; kk < 8; ++kk) { \
            float2 p; \
            p.x = __shfl_xor(a[kk].x, m_); \
            p.y = __shfl_xor(a[kk].y, m_); \
            a[kk] = cfma2(ca_, a[kk], cb_, p); \
        } }

    for (int l = 0; l < NL; ++l) {
        const int g0 = l*NQ;
        CG(g0+0, 4) CG(g0+1, 2) CG(g0+2, 1)          // qubits 0,1,2 (bits 10,9,8)

        #pragma unroll
        for (int k = 0; k < 8; ++k) lds[a0w ^ swzA(k<<8)] = a[k];
        __syncthreads();
        #pragma unroll
        for (int k = 0; k < 8; ++k) a[k] = lds[a1b ^ swzA(k<<5)];
        __syncthreads();
        CG(g0+3, 4) CG(g0+4, 2) CG(g0+5, 1)          // qubits 3,4,5 (bits 7,6,5)

        #pragma unroll
        for (int k = 0; k < 8; ++k) lds[a1b ^ swzA(k<<5)] = a[k];
        __syncthreads();
        #pragma unroll
        for (int k = 0; k < 8; ++k) a[k] = lds[a2b ^ swzA(k<<2)];
        __syncthreads();
        CG(g0+6, 4) CG(g0+7, 2) CG(g0+8, 1)          // qubits 6,7,8 (bits 4,3,2)

        SG(g0+9, 2, (t>>1)&1)                        // qubit 9 (bit 1)
        SG(g0+10, 1, t&1)                            // qubit 10 (bit 0)

        if (l < NL-1) {
            #pragma unroll
            for (int k = 0; k < 8; ++k) lds[a2b ^ swzA(k<<2)] = a[k];
            __syncthreads();
            #pragma unroll
            for (int k = 0; k < 8; ++k)
                a[k] = lds[a3b ^ swzA((k<<8) ^ (k<<7))];   // src = g((k<<8)|t)
            __syncthreads();
        } else {
            #pragma unroll
            for (int k = 0; k < 8; ++k) ws[natb | (k<<2)] = a[k];
        }
    }
    #undef CG
    #undef SG
}

// ========= kernel 2: per-sample 11 RY gates + CNOT perm, 8192 blocks =========
// 128 threads x 16 amps. Two LDS exchanges only; CNOT perm folded into the
// X2 gather; last 3 gates conjugated into o-domain lane butterflies via DPP.
__global__ __launch_bounds__(128, 4) void qnn_last_kernel(
    const float* __restrict__ X,      // (B, NQ)
    const float2* __restrict__ S5,    // shared state, natural order
    float2* __restrict__ out)         // (B, DIM)
{
    __shared__ float2 lds[DIM];
    __shared__ float2 gc[NQ];
    const int b = blockIdx.x;
    const int t = threadIdx.x;        // 7 bits

    if (t < NQ) {
        const float tx = 0.5f * X[(size_t)b*NQ + t];
        gc[t] = make_float2(cosf(tx), sinf(tx));
    }

    // swizzled per-thread LDS bases (GF(2)-linear: base ^ constexpr k-part)
    const int b0 = swzB(t);                           // X1 write  (k<<7)
    const int b1 = swzB(((t>>3)<<7) | (t&7));         // X1 read / X2 write (k<<3)
    const int b3 = swzB(t ^ (t>>1));                  // X2 perm-gather read

    // L0: reg k holds state i = (k<<7)|t  (bits 10..7 local)
    v2f a[16];
    #pragma unroll
    for (int k = 0; k < 16; ++k) {
        const float2 v = S5[(k<<7) | t];
        a[k] = (v2f){v.x, v.y};
    }
    __syncthreads();   // bar1: gc ready

    // real RY on reg bit rb: packed (re,im) -> v_pk_fma_f32
    #define RG(q_, rb_) { \
        const float c = gc[q_].x, s = gc[q_].y; \
        _Pragma("unroll") \
        for (int kk = 0; kk < 16; ++kk) if (!(kk & (rb_))) { \
            const v2f a0 = a[kk], a1 = a[kk|(rb_)]; \
            a[kk]       = c*a0 - s*a1; \
            a[kk|(rb_)] = s*a0 + c*a1; \
        } }

    // o-domain RY on lane-xor CTRL (DPP), role bit r_: 0 -> c*self - s*p,
    // 1 -> c*self + s*p
    #define LGD(q_, CTRL_, r_) { \
        const float c = gc[q_].x, s = gc[q_].y; \
        const float sg = (r_) ? s : -s; \
        _Pragma("unroll") \
        for (int kk = 0; kk < 16; ++kk) { \
            const v2f p = dpp_xor<CTRL_>(a[kk]); \
            a[kk] = c*a[kk] + sg*p; \
        } }

    RG(0, 8) RG(1, 4) RG(2, 2) RG(3, 1)              // qubits 0..3 (bits 10..7)

    // X1 -> L1: i = (t[6:3]<<7)|(k<<3)|t[2:0]
    #pragma unroll
    for (int k = 0; k < 16; ++k)
        lds[b0 ^ swzB(k<<7)] = make_float2(a[k].x, a[k].y);
    __syncthreads();   // bar2
    #pragma unroll
    for (int k = 0; k < 16; ++k) {
        const float2 v = lds[b1 ^ swzB(k<<3)];
        a[k] = (v2f){v.x, v.y};
    }
    RG(4, 8) RG(5, 4) RG(6, 2) RG(7, 1)              // qubits 4..7 (bits 6..3)

    // X2 write: same per-thread slots just read -> no barrier needed
    #pragma unroll
    for (int k = 0; k < 16; ++k)
        lds[b1 ^ swzB(k<<3)] = make_float2(a[k].x, a[k].y);
    __syncthreads();   // bar3
    // perm-fold gather: u[k] = s8[g(o)], o = (k<<7)|t, g linear ->
    // addr = swzB(t^(t>>1)) ^ swzB((k<<7)^(k<<6))
    #pragma unroll
    for (int k = 0; k < 16; ++k) {
        const float2 v = lds[b3 ^ swzB((k<<7) ^ (k<<6))];
        a[k] = (v2f){v.x, v.y};
    }

    // remaining gates (state bits 2,1,0) in o-domain: masks 7,3,1 on lane bits
    LGD(8, 0x141, ((t>>2) ^ (t>>3)) & 1)             // qubit 8: xor7, role t2^t3
    LGD(9, 27,    ((t>>1) ^ (t>>2)) & 1)             // qubit 9: xor3, role t1^t2
    LGD(10, 177,  ( t     ^ (t>>1)) & 1)             // qubit 10: xor1, role t0^t1

    // store: out[(k<<7)|t] -- 512 B contiguous per wave per k
    float2* o = out + (size_t)b * DIM + t;
    #pragma unroll
    for (int k = 0; k < 16; ++k)
        o[k<<7] = make_float2(a[k].x, a[k].y);
    #undef RG
    #undef LGD
}

extern "C" void kernel_launch(void* const* d_in, const int* in_sizes, int n_in,
                              void* d_out, int out_size, void* d_ws, size_t ws_size,
                              hipStream_t stream) {
    const float* X = (const float*)d_in[0];   // (B, NQ) float32
    const float* P = (const float*)d_in[1];   // (NL, NQ, 3) float32
    float2* out = (float2*)d_out;
    float2* ws  = (float2*)d_ws;              // 16 KB shared state
    const int B = in_sizes[0] / NQ;           // 8192
    qnn_shared_kernel<<<1, 256, 0, stream>>>(P, ws);
    qnn_last_kernel<<<B, 128, 0, stream>>>(X, ws, out);
}